// Round 8
// baseline (162.180 us; speedup 1.0000x reference)
//
#include <hip/hip_runtime.h>
#include <hip/hip_bf16.h>
#include <math.h>

#define N_ROWS 12288
#define IN_DIM 512
#define F_DIM  128
#define CH     16          // sorted-order chunk for prefix pipeline
#define NCH    768         // N_ROWS / CH
#define K4T    512         // keys per k-tile in rank phase (24 tiles)

typedef unsigned short ushort_t;
typedef unsigned long long ull_t;
typedef __attribute__((ext_vector_type(8))) short bf16x8;
typedef __attribute__((ext_vector_type(4))) float f32x4;

__device__ __forceinline__ unsigned orderKey(float x) {
    unsigned b = __float_as_uint(x);
    return (b & 0x80000000u) ? ~b : (b | 0x80000000u);
}

// ---------------------------------------------------------------------------
// K1: per-feature norm + scale, fold scale into v, split to bf16 hi/lo.
// ---------------------------------------------------------------------------
__global__ __launch_bounds__(64) void k1_prep(const float* __restrict__ v,
                                              const float* __restrict__ g,
                                              ushort_t* __restrict__ vh,
                                              ushort_t* __restrict__ vl) {
    int f = blockIdx.x;
    int lane = threadIdx.x;
    float sum = 0.f;
    for (int k = lane; k < IN_DIM; k += 64) {
        float x = v[(size_t)f * IN_DIM + k];
        sum += x * x;
    }
    #pragma unroll
    for (int off = 32; off > 0; off >>= 1) sum += __shfl_xor(sum, off);
    float sc = g[f] / sqrtf(sum);
    for (int k = lane; k < IN_DIM; k += 64) {
        float w = v[(size_t)f * IN_DIM + k] * sc;
        __hip_bfloat16 hb = __float2bfloat16(w);
        float hf = __bfloat162float(hb);
        __hip_bfloat16 lb = __float2bfloat16(w - hf);
        vh[(size_t)f * IN_DIM + k] = *(ushort_t*)&hb;
        vl[(size_t)f * IN_DIM + k] = *(ushort_t*)&lb;
    }
}

// ---------------------------------------------------------------------------
// K2: z = x @ w^T + b via bf16x3 split MFMA (16x16x32), fused s/d/keys +
// rankAcc zeroing. Block: M=16 x N=128, BK=64, 256 threads (4 waves,
// wave n-tile 32). 768 blocks, LDS 41.5 KB -> 3 blocks/CU.
// ---------------------------------------------------------------------------
#define LDSS 72   // LDS row stride in bf16 elems (144B)
__global__ __launch_bounds__(256) void k2_mfma(const float* __restrict__ x,
                                               const ushort_t* __restrict__ vh,
                                               const ushort_t* __restrict__ vl,
                                               const float* __restrict__ b,
                                               const float* __restrict__ aw,
                                               float* __restrict__ z,
                                               float* __restrict__ s,
                                               float* __restrict__ d,
                                               ull_t* __restrict__ keys,
                                               ull_t* __restrict__ rankAcc) {
    __shared__ ushort_t sh[(16 + 16 + 128 + 128) * LDSS];   // 41472 B
    ushort_t* xh_s = sh;
    ushort_t* xl_s = sh + 16 * LDSS;
    ushort_t* vh_s = sh + 32 * LDSS;
    ushort_t* vl_s = sh + (32 + 128) * LDSS;

    const int t = threadIdx.x;
    const int wave = t >> 6, lane = t & 63;
    const int i0 = blockIdx.x * 16;
    const int n0 = wave * 32;
    const int r16 = t >> 4;   // 0..15 (x row)
    const int kg4 = t & 15;   // x cols kg4*4

    f32x4 acc[2] = {};        // [nt]

    if (t < 16) rankAcc[i0 + t] = 0ULL;

    for (int k0 = 0; k0 < IN_DIM; k0 += 64) {
        {   // x tile 16 x 64: 4 floats per thread, split hi/lo
            float4 f0 = *(const float4*)&x[(size_t)(i0 + r16) * IN_DIM + k0 + kg4 * 4];
            float ff[4] = {f0.x, f0.y, f0.z, f0.w};
            ushort_t h[4], lo[4];
            #pragma unroll
            for (int e = 0; e < 4; ++e) {
                __hip_bfloat16 hb = __float2bfloat16(ff[e]);
                float hf = __bfloat162float(hb);
                __hip_bfloat16 lb = __float2bfloat16(ff[e] - hf);
                h[e]  = *(ushort_t*)&hb;
                lo[e] = *(ushort_t*)&lb;
            }
            *(uint2*)&xh_s[r16 * LDSS + kg4 * 4] = *(uint2*)h;
            *(uint2*)&xl_s[r16 * LDSS + kg4 * 4] = *(uint2*)lo;
        }
        // v tile 128 x 64 hi/lo: 1024 groups of 8 bf16, 4 per thread
        #pragma unroll
        for (int it = 0; it < 4; ++it) {
            int gidx = t + it * 256;
            int row = gidx >> 3, kgg = gidx & 7;
            uint4 hv = *(const uint4*)&vh[(size_t)row * IN_DIM + k0 + kgg * 8];
            uint4 lv = *(const uint4*)&vl[(size_t)row * IN_DIM + k0 + kgg * 8];
            *(uint4*)&vh_s[row * LDSS + kgg * 8] = hv;
            *(uint4*)&vl_s[row * LDSS + kgg * 8] = lv;
        }
        __syncthreads();
        #pragma unroll
        for (int sub = 0; sub < 2; ++sub) {
            int kb = sub * 32 + (lane >> 4) * 8;
            int mrow = lane & 15;
            bf16x8 ah = *(const bf16x8*)&xh_s[mrow * LDSS + kb];
            bf16x8 al = *(const bf16x8*)&xl_s[mrow * LDSS + kb];
            bf16x8 bh[2], bl[2];
            #pragma unroll
            for (int nt = 0; nt < 2; ++nt) {
                int row = n0 + nt * 16 + (lane & 15);
                bh[nt] = *(const bf16x8*)&vh_s[row * LDSS + kb];
                bl[nt] = *(const bf16x8*)&vl_s[row * LDSS + kb];
            }
            #pragma unroll
            for (int nt = 0; nt < 2; ++nt) {
                acc[nt] = __builtin_amdgcn_mfma_f32_16x16x32_bf16(ah, bh[nt], acc[nt], 0, 0, 0);
                acc[nt] = __builtin_amdgcn_mfma_f32_16x16x32_bf16(ah, bl[nt], acc[nt], 0, 0, 0);
                acc[nt] = __builtin_amdgcn_mfma_f32_16x16x32_bf16(al, bh[nt], acc[nt], 0, 0, 0);
            }
        }
        __syncthreads();
    }

    // ---- epilogue: bias add, store z, keep tile in LDS for s/d ----
    float* zt = (float*)sh;          // 16 x 132 f32 (reuse staging LDS)
    #pragma unroll
    for (int nt = 0; nt < 2; ++nt) {
        int n = n0 + nt * 16 + (lane & 15);
        float bb = b[n];
        #pragma unroll
        for (int r = 0; r < 4; ++r) {
            int mrow = (lane >> 4) * 4 + r;
            float val = acc[nt][r] + bb;
            z[(size_t)(i0 + mrow) * F_DIM + n] = val;
            zt[mrow * 132 + n] = val;
        }
    }
    __syncthreads();
    // s/d/keys: 4 waves x 4 rows each
    float awS0 = aw[lane], awS1 = aw[64 + lane];
    float awD0 = aw[F_DIM + lane], awD1 = aw[F_DIM + 64 + lane];
    #pragma unroll
    for (int rr = 0; rr < 4; ++rr) {
        int row = wave * 4 + rr;
        float z0 = zt[row * 132 + lane];
        float z1 = zt[row * 132 + 64 + lane];
        float ss = z0 * awS0 + z1 * awS1;
        float dd = z0 * awD0 + z1 * awD1;
        #pragma unroll
        for (int off = 32; off > 0; off >>= 1) {
            ss += __shfl_xor(ss, off);
            dd += __shfl_xor(dd, off);
        }
        if (lane == 0) {
            int i = i0 + row;
            s[i] = ss;
            d[i] = dd;
            keys[i] = ((ull_t)orderKey(dd) << 32) | (unsigned)i;
        }
    }
}

// ---------------------------------------------------------------------------
// K4: fused rank-count + scatter. Each (jc, kt) block adds its partial count
// into acc[j] packed as {counter<<40 | sum}; the 24th contributor owns the
// final rank and scatters perm/ed/soi inline.
// ---------------------------------------------------------------------------
__global__ __launch_bounds__(256) void k4_rank(const ull_t* __restrict__ keys,
                                               const float* __restrict__ dvec,
                                               ull_t* __restrict__ acc,
                                               int* __restrict__ perm,
                                               float* __restrict__ ed,
                                               unsigned* __restrict__ soi) {
    int j = blockIdx.x * 256 + threadIdx.x;
    ull_t kj = keys[j];
    const ull_t* p = keys + blockIdx.y * K4T;
    int cr = 0;
    for (int kk = 0; kk < K4T; kk += 8) {
        ull_t kv[8];
        #pragma unroll
        for (int e = 0; e < 8; ++e) kv[e] = p[kk + e];
        #pragma unroll
        for (int e = 0; e < 8; ++e) cr += (kv[e] < kj);
    }
    ull_t old = atomicAdd(&acc[j], (ull_t)cr | (1ULL << 40));
    if ((old >> 40) == 23) {       // we are the last contributor
        int r = (int)((old & ((1ULL << 40) - 1)) + (unsigned)cr);
        perm[r] = j;
        ed[r] = expf(dvec[j]);
        soi[r] = (unsigned)(kj >> 32);
    }
}

// ---------------------------------------------------------------------------
// K5b: per-chunk sums over CH=16 sorted rows (768 blocks x 128)
// ---------------------------------------------------------------------------
__global__ __launch_bounds__(128) void k5b_chunksum(const float* __restrict__ z,
                                                    const int* __restrict__ perm,
                                                    const float* __restrict__ ed,
                                                    float* __restrict__ chEZ,
                                                    float* __restrict__ chZ,
                                                    float* __restrict__ chE) {
    int k = blockIdx.x, f = threadIdx.x;
    int p0 = k * CH;
    float aez = 0.f, az = 0.f;
    #pragma unroll 4
    for (int q = 0; q < CH; ++q) {
        float e  = ed[p0 + q];
        float zv = z[(size_t)perm[p0 + q] * F_DIM + f];
        aez = fmaf(e, zv, aez);
        az += zv;
    }
    chEZ[(size_t)k * F_DIM + f] = aez;
    chZ [(size_t)k * F_DIM + f] = az;
    if (f < CH) {
        float e = ed[p0 + f];
        #pragma unroll
        for (int off = 8; off > 0; off >>= 1) e += __shfl_xor(e, off);
        if (f == 0) chE[k] = e;
    }
}

// ---------------------------------------------------------------------------
// K5c: exclusive prefix over NCH=768 chunk sums; totals at index NCH.
// grid 129 x 64: blocks 0..127 one f-column of chEZ and chZ; block 128 chE.
// ---------------------------------------------------------------------------
__global__ __launch_bounds__(64) void k5c_scan(float* __restrict__ chEZ,
                                               float* __restrict__ chZ,
                                               float* __restrict__ chE) {
    int bx = blockIdx.x;
    int lane = threadIdx.x;
    int npass = (bx < F_DIM) ? 2 : 1;
    for (int pass = 0; pass < npass; ++pass) {
        float* arr = (bx == F_DIM) ? chE : (pass == 0 ? chEZ : chZ);
        size_t str = (bx == F_DIM) ? 1 : F_DIM;
        size_t col = (bx == F_DIM) ? 0 : (size_t)bx;
        float vv[12];
        #pragma unroll
        for (int e = 0; e < 12; ++e)
            vv[e] = arr[(size_t)(lane * 12 + e) * str + col];
        float run = 0.f;
        #pragma unroll
        for (int e = 0; e < 12; ++e) { float tmp = vv[e]; vv[e] = run; run += tmp; }
        float incl = run;
        #pragma unroll
        for (int off = 1; off < 64; off <<= 1) {
            float o = __shfl_up(incl, off);
            if (lane >= off) incl += o;
        }
        float excl = incl - run;
        #pragma unroll
        for (int e = 0; e < 12; ++e)
            arr[(size_t)(lane * 12 + e) * str + col] = excl + vv[e];
        if (lane == 63)
            arr[(size_t)NCH * str + col] = incl;   // grand total
    }
}

// ---------------------------------------------------------------------------
// K6: per row i (2 rows per 256-thread block) —
//   c = upper_bound(soi, orderKey(-s_i)); partial = chunk prefix + remainder
//   z2 = (es*sufEZ + preZ)/(es*sufE + c) + z ; out = softmax(z2)
// ---------------------------------------------------------------------------
__global__ __launch_bounds__(256) void k6_final(const float* __restrict__ z,
                                                const float* __restrict__ s,
                                                const int* __restrict__ perm,
                                                const float* __restrict__ ed,
                                                const unsigned* __restrict__ soi,
                                                const float* __restrict__ chEZ,
                                                const float* __restrict__ chZ,
                                                const float* __restrict__ chE,
                                                float* __restrict__ out) {
    __shared__ float redmx[4], redsum[4];
    int t = threadIdx.x;
    int grp = t >> 7;             // row within block
    int f = t & 127;
    int wave = t >> 6, lane = t & 63;
    int i = blockIdx.x * 2 + grp;

    float si = s[i];
    unsigned ot = orderKey(-si);
    int lo = 0, hi = N_ROWS;
    while (lo < hi) {
        int mid = (lo + hi) >> 1;
        if (soi[mid] <= ot) lo = mid + 1; else hi = mid;
    }
    int c = lo;
    int kc = c >> 4, r = c & 15, p0 = kc << 4;

    float bEZ = chEZ[(size_t)kc * F_DIM + f];
    float bZ  = chZ [(size_t)kc * F_DIM + f];
    float bE  = chE[kc];
    for (int q = 0; q < r; ++q) {
        float e  = ed[p0 + q];
        float zv = z[(size_t)perm[p0 + q] * F_DIM + f];
        bEZ = fmaf(e, zv, bEZ);
        bZ += zv;
        bE += e;
    }
    float totE  = chE[NCH];
    float totEZ = chEZ[(size_t)NCH * F_DIM + f];
    float es = expf(si);
    float D   = fmaf(es, totE - bE, (float)c);
    float num = fmaf(es, totEZ - bEZ, bZ);
    float z2  = num / D + z[(size_t)i * F_DIM + f];

    float mx = z2;
    #pragma unroll
    for (int off = 32; off > 0; off >>= 1) mx = fmaxf(mx, __shfl_xor(mx, off));
    if (lane == 0) redmx[wave] = mx;
    __syncthreads();
    mx = fmaxf(redmx[grp * 2], redmx[grp * 2 + 1]);

    float ex = expf(z2 - mx);
    float sm = ex;
    #pragma unroll
    for (int off = 32; off > 0; off >>= 1) sm += __shfl_xor(sm, off);
    if (lane == 0) redsum[wave] = sm;
    __syncthreads();
    sm = redsum[grp * 2] + redsum[grp * 2 + 1];

    out[(size_t)i * F_DIM + f] = ex / sm;
}

// ---------------------------------------------------------------------------
extern "C" void kernel_launch(void* const* d_in, const int* in_sizes, int n_in,
                              void* d_out, int out_size, void* d_ws, size_t ws_size,
                              hipStream_t stream) {
    const float* x  = (const float*)d_in[0];
    const float* v  = (const float*)d_in[1];
    const float* g  = (const float*)d_in[2];
    const float* b  = (const float*)d_in[3];
    const float* aw = (const float*)d_in[4];
    float* out = (float*)d_out;

    float* wsf = (float*)d_ws;
    size_t off = 0;
    float* z     = wsf + off;  off += (size_t)N_ROWS * F_DIM;
    float* s     = wsf + off;  off += N_ROWS;
    float* d     = wsf + off;  off += N_ROWS;
    ull_t* keys  = (ull_t*)(wsf + off);  off += 2 * N_ROWS;
    ull_t* rankA = (ull_t*)(wsf + off);  off += 2 * N_ROWS;
    int*   perm  = (int*)(wsf + off);  off += N_ROWS;
    float* ed    = wsf + off;  off += N_ROWS;
    unsigned* soi = (unsigned*)(wsf + off);  off += N_ROWS;
    float* chEZ  = wsf + off;  off += (size_t)(NCH + 1) * F_DIM;
    float* chZ   = wsf + off;  off += (size_t)(NCH + 1) * F_DIM;
    float* chE   = wsf + off;  off += NCH + 4;
    ushort_t* vh = (ushort_t*)(wsf + off);  off += (F_DIM * IN_DIM) / 2;
    ushort_t* vl = (ushort_t*)(wsf + off);  off += (F_DIM * IN_DIM) / 2;

    k1_prep<<<F_DIM, 64, 0, stream>>>(v, g, vh, vl);
    k2_mfma<<<N_ROWS / 16, 256, 0, stream>>>(x, vh, vl, b, aw, z, s, d, keys, rankA);
    k4_rank<<<dim3(N_ROWS / 256, N_ROWS / K4T), 256, 0, stream>>>(keys, d, rankA, perm, ed, soi);
    k5b_chunksum<<<NCH, 128, 0, stream>>>(z, perm, ed, chEZ, chZ, chE);
    k5c_scan<<<F_DIM + 1, 64, 0, stream>>>(chEZ, chZ, chE);
    k6_final<<<N_ROWS / 2, 256, 0, stream>>>(z, s, perm, ed, soi, chEZ, chZ, chE, out);
}

// Round 9
// 161.604 us; speedup vs baseline: 1.0036x; 1.0036x over previous
//
#include <hip/hip_runtime.h>
#include <hip/hip_bf16.h>
#include <math.h>

#define N_ROWS 12288
#define IN_DIM 512
#define F_DIM  128
#define CH     16          // sorted-order chunk for prefix pipeline
#define NCH    768         // N_ROWS / CH
#define K4T    512         // keys per k-tile in rank phase

typedef unsigned short ushort_t;
typedef unsigned long long ull_t;
typedef __attribute__((ext_vector_type(8))) short bf16x8;
typedef __attribute__((ext_vector_type(4))) float f32x4;

__device__ __forceinline__ unsigned orderKey(float x) {
    unsigned b = __float_as_uint(x);
    return (b & 0x80000000u) ? ~b : (b | 0x80000000u);
}

// ---------------------------------------------------------------------------
// K2: z = x @ w^T + b via bf16x3 split MFMA (16x16x32), with k1 folded in:
// per-block scale compute (v is 256 KB, L2-resident) + on-the-fly v->bf16
// hi/lo conversion during staging. Fused s/d/keys epilogue + rank zeroing.
// Block: M=32 x N=128, BK=64, 256 threads (4 waves), wave tile 32x32.
// 384 blocks, LDS ~46.6 KB.
// ---------------------------------------------------------------------------
#define LDSS 72   // LDS row stride in bf16 elems (144B)
__global__ __launch_bounds__(256) void k2_mfma(const float* __restrict__ x,
                                               const float* __restrict__ v,
                                               const float* __restrict__ g,
                                               const float* __restrict__ b,
                                               const float* __restrict__ aw,
                                               float* __restrict__ z,
                                               float* __restrict__ s,
                                               float* __restrict__ d,
                                               ull_t* __restrict__ keys,
                                               int* __restrict__ rank) {
    __shared__ ushort_t sh[(32 + 32 + 128 + 128) * LDSS];   // 46080 B
    __shared__ float sscale[F_DIM];
    ushort_t* xh_s = sh;
    ushort_t* xl_s = sh + 32 * LDSS;
    ushort_t* vh_s = sh + 64 * LDSS;
    ushort_t* vl_s = sh + (64 + 128) * LDSS;

    const int t = threadIdx.x;
    const int wave = t >> 6, lane = t & 63;
    const int i0 = blockIdx.x * 32;
    const int n0 = wave * 32;
    const int r8 = t >> 3;   // 0..31 (x row)
    const int kg = t & 7;    // x col group, cols kg*8..+7

    f32x4 acc[2][2] = {};    // [mt][nt]

    if (t < 32) rank[i0 + t] = 0;

    // ---- per-block scale[f] = g[f]/||v_f|| (2 threads per feature) ----
    {
        int f = t >> 1, half = t & 1;
        const float* vp = &v[(size_t)f * IN_DIM + half * 256];
        float sum = 0.f;
        #pragma unroll 8
        for (int k = 0; k < 256; k += 4) {
            float4 q = *(const float4*)&vp[k];
            sum += q.x * q.x + q.y * q.y + q.z * q.z + q.w * q.w;
        }
        sum += __shfl_xor(sum, 1);
        if (half == 0) sscale[f] = g[f] / sqrtf(sum);
    }
    __syncthreads();

    for (int k0 = 0; k0 < IN_DIM; k0 += 64) {
        {   // x tile 32 x 64: 8 floats per thread, split hi/lo
            const float* gp = &x[(size_t)(i0 + r8) * IN_DIM + k0 + kg * 8];
            float4 f0 = *(const float4*)gp;
            float4 f1 = *(const float4*)(gp + 4);
            float ff[8] = {f0.x, f0.y, f0.z, f0.w, f1.x, f1.y, f1.z, f1.w};
            ushort_t h[8], lo[8];
            #pragma unroll
            for (int e = 0; e < 8; ++e) {
                __hip_bfloat16 hb = __float2bfloat16(ff[e]);
                float hf = __bfloat162float(hb);
                __hip_bfloat16 lb = __float2bfloat16(ff[e] - hf);
                h[e]  = *(ushort_t*)&hb;
                lo[e] = *(ushort_t*)&lb;
            }
            *(uint4*)&xh_s[r8 * LDSS + kg * 8] = *(uint4*)h;
            *(uint4*)&xl_s[r8 * LDSS + kg * 8] = *(uint4*)lo;
        }
        // v tile 128 x 64: read f32, scale, split hi/lo on the fly
        #pragma unroll
        for (int it = 0; it < 4; ++it) {
            int gidx = t + it * 256;
            int row = gidx >> 3, kgg = gidx & 7;
            const float* gp = &v[(size_t)row * IN_DIM + k0 + kgg * 8];
            float4 f0 = *(const float4*)gp;
            float4 f1 = *(const float4*)(gp + 4);
            float sc = sscale[row];
            float ff[8] = {f0.x, f0.y, f0.z, f0.w, f1.x, f1.y, f1.z, f1.w};
            ushort_t h[8], lo[8];
            #pragma unroll
            for (int e = 0; e < 8; ++e) {
                float w = ff[e] * sc;
                __hip_bfloat16 hb = __float2bfloat16(w);
                float hf = __bfloat162float(hb);
                __hip_bfloat16 lb = __float2bfloat16(w - hf);
                h[e]  = *(ushort_t*)&hb;
                lo[e] = *(ushort_t*)&lb;
            }
            *(uint4*)&vh_s[row * LDSS + kgg * 8] = *(uint4*)h;
            *(uint4*)&vl_s[row * LDSS + kgg * 8] = *(uint4*)lo;
        }
        __syncthreads();
        #pragma unroll
        for (int sub = 0; sub < 2; ++sub) {
            int kb = sub * 32 + (lane >> 4) * 8;
            bf16x8 ah[2], al[2], bh[2], bl[2];
            #pragma unroll
            for (int mt = 0; mt < 2; ++mt) {
                int row = mt * 16 + (lane & 15);
                ah[mt] = *(const bf16x8*)&xh_s[row * LDSS + kb];
                al[mt] = *(const bf16x8*)&xl_s[row * LDSS + kb];
            }
            #pragma unroll
            for (int nt = 0; nt < 2; ++nt) {
                int row = n0 + nt * 16 + (lane & 15);
                bh[nt] = *(const bf16x8*)&vh_s[row * LDSS + kb];
                bl[nt] = *(const bf16x8*)&vl_s[row * LDSS + kb];
            }
            #pragma unroll
            for (int mt = 0; mt < 2; ++mt)
                #pragma unroll
                for (int nt = 0; nt < 2; ++nt) {
                    acc[mt][nt] = __builtin_amdgcn_mfma_f32_16x16x32_bf16(ah[mt], bh[nt], acc[mt][nt], 0, 0, 0);
                    acc[mt][nt] = __builtin_amdgcn_mfma_f32_16x16x32_bf16(ah[mt], bl[nt], acc[mt][nt], 0, 0, 0);
                    acc[mt][nt] = __builtin_amdgcn_mfma_f32_16x16x32_bf16(al[mt], bh[nt], acc[mt][nt], 0, 0, 0);
                }
        }
        __syncthreads();
    }

    // ---- epilogue: bias add, store z, keep tile in LDS for s/d ----
    float* zt = (float*)sh;          // 32 x 132 f32 (reuse staging LDS)
    #pragma unroll
    for (int nt = 0; nt < 2; ++nt) {
        int n = n0 + nt * 16 + (lane & 15);
        float bb = b[n];
        #pragma unroll
        for (int mt = 0; mt < 2; ++mt)
            #pragma unroll
            for (int r = 0; r < 4; ++r) {
                int mrow = mt * 16 + (lane >> 4) * 4 + r;
                float val = acc[mt][nt][r] + bb;
                z[(size_t)(i0 + mrow) * F_DIM + n] = val;
                zt[mrow * 132 + n] = val;
            }
    }
    __syncthreads();
    // s/d/keys: 4 waves x 8 rows each
    float awS0 = aw[lane], awS1 = aw[64 + lane];
    float awD0 = aw[F_DIM + lane], awD1 = aw[F_DIM + 64 + lane];
    #pragma unroll
    for (int rr = 0; rr < 8; ++rr) {
        int row = wave * 8 + rr;
        float z0 = zt[row * 132 + lane];
        float z1 = zt[row * 132 + 64 + lane];
        float ss = z0 * awS0 + z1 * awS1;
        float dd = z0 * awD0 + z1 * awD1;
        #pragma unroll
        for (int off = 32; off > 0; off >>= 1) {
            ss += __shfl_xor(ss, off);
            dd += __shfl_xor(dd, off);
        }
        if (lane == 0) {
            int i = i0 + row;
            s[i] = ss;
            d[i] = dd;
            keys[i] = ((ull_t)orderKey(dd) << 32) | (unsigned)i;
        }
    }
}

// ---------------------------------------------------------------------------
// K4: rank[j] = #{k : key_k < key_j}. Keys batched 8 (uniform -> scalar
// loads); grid (48, 24) = 1152 blocks; fire-and-forget atomic partials.
// ---------------------------------------------------------------------------
__global__ __launch_bounds__(256) void k4_rank(const ull_t* __restrict__ keys,
                                               int* __restrict__ rank) {
    int j = blockIdx.x * 256 + threadIdx.x;
    ull_t kj = keys[j];
    const ull_t* p = keys + blockIdx.y * K4T;
    int cr = 0;
    for (int kk = 0; kk < K4T; kk += 8) {
        ull_t kv[8];
        #pragma unroll
        for (int e = 0; e < 8; ++e) kv[e] = p[kk + e];
        #pragma unroll
        for (int e = 0; e < 8; ++e) cr += (kv[e] < kj);
    }
    atomicAdd(&rank[j], cr);
}

// ---------------------------------------------------------------------------
// K5a: scatter into sorted order: perm, ed = exp(d), soi = orderable key
// ---------------------------------------------------------------------------
__global__ __launch_bounds__(256) void k5a_scatter(const float* __restrict__ d,
                                                   const int* __restrict__ rank,
                                                   int* __restrict__ perm,
                                                   float* __restrict__ ed,
                                                   unsigned* __restrict__ soi) {
    int j = blockIdx.x * 256 + threadIdx.x;
    int r = rank[j];
    float dj = d[j];
    perm[r] = j;
    ed[r] = expf(dj);
    soi[r] = orderKey(dj);
}

// ---------------------------------------------------------------------------
// K5b: per-chunk sums over CH=16 sorted rows (768 blocks x 128)
// ---------------------------------------------------------------------------
__global__ __launch_bounds__(128) void k5b_chunksum(const float* __restrict__ z,
                                                    const int* __restrict__ perm,
                                                    const float* __restrict__ ed,
                                                    float* __restrict__ chEZ,
                                                    float* __restrict__ chZ,
                                                    float* __restrict__ chE) {
    int k = blockIdx.x, f = threadIdx.x;
    int p0 = k * CH;
    float aez = 0.f, az = 0.f;
    #pragma unroll 4
    for (int q = 0; q < CH; ++q) {
        float e  = ed[p0 + q];
        float zv = z[(size_t)perm[p0 + q] * F_DIM + f];
        aez = fmaf(e, zv, aez);
        az += zv;
    }
    chEZ[(size_t)k * F_DIM + f] = aez;
    chZ [(size_t)k * F_DIM + f] = az;
    if (f < CH) {
        float e = ed[p0 + f];
        #pragma unroll
        for (int off = 8; off > 0; off >>= 1) e += __shfl_xor(e, off);
        if (f == 0) chE[k] = e;
    }
}

// ---------------------------------------------------------------------------
// K5c: exclusive prefix over NCH=768 chunk sums; totals land at index NCH.
// grid 129 x 64: blocks 0..127 handle one f-column of chEZ and chZ;
// block 128 handles chE. Each lane owns 12 chunks.
// ---------------------------------------------------------------------------
__global__ __launch_bounds__(64) void k5c_scan(float* __restrict__ chEZ,
                                               float* __restrict__ chZ,
                                               float* __restrict__ chE) {
    int bx = blockIdx.x;
    int lane = threadIdx.x;
    int npass = (bx < F_DIM) ? 2 : 1;
    for (int pass = 0; pass < npass; ++pass) {
        float* arr = (bx == F_DIM) ? chE : (pass == 0 ? chEZ : chZ);
        size_t str = (bx == F_DIM) ? 1 : F_DIM;
        size_t col = (bx == F_DIM) ? 0 : (size_t)bx;
        float vv[12];
        #pragma unroll
        for (int e = 0; e < 12; ++e)
            vv[e] = arr[(size_t)(lane * 12 + e) * str + col];
        float run = 0.f;
        #pragma unroll
        for (int e = 0; e < 12; ++e) { float tmp = vv[e]; vv[e] = run; run += tmp; }
        float incl = run;
        #pragma unroll
        for (int off = 1; off < 64; off <<= 1) {
            float o = __shfl_up(incl, off);
            if (lane >= off) incl += o;
        }
        float excl = incl - run;
        #pragma unroll
        for (int e = 0; e < 12; ++e)
            arr[(size_t)(lane * 12 + e) * str + col] = excl + vv[e];
        if (lane == 63)
            arr[(size_t)NCH * str + col] = incl;   // grand total
    }
}

// ---------------------------------------------------------------------------
// K6: per row i —
//   c = upper_bound(soi, orderKey(-s_i))  (binary search, 14 steps)
//   partials at c = chunk prefix[kc] + on-the-fly remainder over <=15 rows
//   z2 = (es*sufEZ + preZ)/(es*sufE + c) + z ; out = softmax(z2)
// ---------------------------------------------------------------------------
__global__ __launch_bounds__(128) void k6_final(const float* __restrict__ z,
                                                const float* __restrict__ s,
                                                const int* __restrict__ perm,
                                                const float* __restrict__ ed,
                                                const unsigned* __restrict__ soi,
                                                const float* __restrict__ chEZ,
                                                const float* __restrict__ chZ,
                                                const float* __restrict__ chE,
                                                float* __restrict__ out) {
    __shared__ float redmx[2], redsum[2];
    int i = blockIdx.x, f = threadIdx.x;
    int wave = f >> 6, lane = f & 63;

    float si = s[i];
    unsigned ot = orderKey(-si);
    int lo = 0, hi = N_ROWS;
    while (lo < hi) {
        int mid = (lo + hi) >> 1;
        if (soi[mid] <= ot) lo = mid + 1; else hi = mid;
    }
    int c = lo;
    int kc = c >> 4, r = c & 15, p0 = kc << 4;

    float bEZ = chEZ[(size_t)kc * F_DIM + f];
    float bZ  = chZ [(size_t)kc * F_DIM + f];
    float bE  = chE[kc];
    for (int q = 0; q < r; ++q) {
        float e  = ed[p0 + q];
        float zv = z[(size_t)perm[p0 + q] * F_DIM + f];
        bEZ = fmaf(e, zv, bEZ);
        bZ += zv;
        bE += e;
    }
    float totE  = chE[NCH];
    float totEZ = chEZ[(size_t)NCH * F_DIM + f];
    float es = expf(si);
    float D   = fmaf(es, totE - bE, (float)c);
    float num = fmaf(es, totEZ - bEZ, bZ);
    float z2  = num / D + z[(size_t)i * F_DIM + f];

    float mx = z2;
    #pragma unroll
    for (int off = 32; off > 0; off >>= 1) mx = fmaxf(mx, __shfl_xor(mx, off));
    if (lane == 0) redmx[wave] = mx;
    __syncthreads();
    mx = fmaxf(redmx[0], redmx[1]);

    float ex = expf(z2 - mx);
    float sm = ex;
    #pragma unroll
    for (int off = 32; off > 0; off >>= 1) sm += __shfl_xor(sm, off);
    if (lane == 0) redsum[wave] = sm;
    __syncthreads();
    sm = redsum[0] + redsum[1];

    out[(size_t)i * F_DIM + f] = ex / sm;
}

// ---------------------------------------------------------------------------
extern "C" void kernel_launch(void* const* d_in, const int* in_sizes, int n_in,
                              void* d_out, int out_size, void* d_ws, size_t ws_size,
                              hipStream_t stream) {
    const float* x  = (const float*)d_in[0];
    const float* v  = (const float*)d_in[1];
    const float* g  = (const float*)d_in[2];
    const float* b  = (const float*)d_in[3];
    const float* aw = (const float*)d_in[4];
    float* out = (float*)d_out;

    float* wsf = (float*)d_ws;
    size_t off = 0;
    float* z     = wsf + off;  off += (size_t)N_ROWS * F_DIM;
    float* s     = wsf + off;  off += N_ROWS;
    float* d     = wsf + off;  off += N_ROWS;
    ull_t* keys  = (ull_t*)(wsf + off);  off += 2 * N_ROWS;
    int*   rank  = (int*)(wsf + off);  off += N_ROWS;
    int*   perm  = (int*)(wsf + off);  off += N_ROWS;
    float* ed    = wsf + off;  off += N_ROWS;
    unsigned* soi = (unsigned*)(wsf + off);  off += N_ROWS;
    float* chEZ  = wsf + off;  off += (size_t)(NCH + 1) * F_DIM;
    float* chZ   = wsf + off;  off += (size_t)(NCH + 1) * F_DIM;
    float* chE   = wsf + off;  off += NCH + 4;

    k2_mfma<<<N_ROWS / 32, 256, 0, stream>>>(x, v, g, b, aw, z, s, d, keys, rank);
    k4_rank<<<dim3(N_ROWS / 256, N_ROWS / K4T), 256, 0, stream>>>(keys, rank);
    k5a_scatter<<<N_ROWS / 256, 256, 0, stream>>>(d, rank, perm, ed, soi);
    k5b_chunksum<<<NCH, 128, 0, stream>>>(z, perm, ed, chEZ, chZ, chE);
    k5c_scan<<<F_DIM + 1, 64, 0, stream>>>(chEZ, chZ, chE);
    k6_final<<<N_ROWS, 128, 0, stream>>>(z, s, perm, ed, soi, chEZ, chZ, chE, out);
}

// Round 10
// 144.288 us; speedup vs baseline: 1.1240x; 1.1200x over previous
//
#include <hip/hip_runtime.h>
#include <hip/hip_bf16.h>
#include <math.h>

#define N_ROWS 12288
#define IN_DIM 512
#define F_DIM  128
#define CH     16          // sorted-order chunk for prefix pipeline
#define NCH    768         // N_ROWS / CH
#define K4T    512         // keys per k-tile in rank phase

typedef unsigned short ushort_t;
typedef unsigned long long ull_t;
typedef __attribute__((ext_vector_type(8))) short bf16x8;
typedef __attribute__((ext_vector_type(4))) float f32x4;

__device__ __forceinline__ unsigned orderKey(float x) {
    unsigned b = __float_as_uint(x);
    return (b & 0x80000000u) ? ~b : (b | 0x80000000u);
}

// ---------------------------------------------------------------------------
// K1: per-feature norm + scale, fold scale into v, split to bf16 hi/lo.
// (Kept separate: fusing into k2 converts v redundantly per block — measured
//  +16 us in round 9. One-shot conversion here is the cheapest form.)
// ---------------------------------------------------------------------------
__global__ __launch_bounds__(64) void k1_prep(const float* __restrict__ v,
                                              const float* __restrict__ g,
                                              ushort_t* __restrict__ vh,
                                              ushort_t* __restrict__ vl) {
    int f = blockIdx.x;
    int lane = threadIdx.x;
    float sum = 0.f;
    for (int k = lane; k < IN_DIM; k += 64) {
        float x = v[(size_t)f * IN_DIM + k];
        sum += x * x;
    }
    #pragma unroll
    for (int off = 32; off > 0; off >>= 1) sum += __shfl_xor(sum, off);
    float sc = g[f] / sqrtf(sum);
    for (int k = lane; k < IN_DIM; k += 64) {
        float w = v[(size_t)f * IN_DIM + k] * sc;
        __hip_bfloat16 hb = __float2bfloat16(w);
        float hf = __bfloat162float(hb);
        __hip_bfloat16 lb = __float2bfloat16(w - hf);
        vh[(size_t)f * IN_DIM + k] = *(ushort_t*)&hb;
        vl[(size_t)f * IN_DIM + k] = *(ushort_t*)&lb;
    }
}

// ---------------------------------------------------------------------------
// K2: z = x @ w^T + b via bf16x3 split MFMA (16x16x32), fused s/d/keys +
// rank zeroing. Block: M=32 x N=128, BK=64, 256 threads (4 waves),
// wave tile 32x32 (12 MFMA per 8 ds_read_b128). 384 blocks, LDS 46 KB.
// ---------------------------------------------------------------------------
#define LDSS 72   // LDS row stride in bf16 elems (144B)
__global__ __launch_bounds__(256) void k2_mfma(const float* __restrict__ x,
                                               const ushort_t* __restrict__ vh,
                                               const ushort_t* __restrict__ vl,
                                               const float* __restrict__ b,
                                               const float* __restrict__ aw,
                                               float* __restrict__ z,
                                               float* __restrict__ s,
                                               float* __restrict__ d,
                                               ull_t* __restrict__ keys,
                                               int* __restrict__ rank) {
    __shared__ ushort_t sh[(32 + 32 + 128 + 128) * LDSS];   // 46080 B
    ushort_t* xh_s = sh;
    ushort_t* xl_s = sh + 32 * LDSS;
    ushort_t* vh_s = sh + 64 * LDSS;
    ushort_t* vl_s = sh + (64 + 128) * LDSS;

    const int t = threadIdx.x;
    const int wave = t >> 6, lane = t & 63;
    const int i0 = blockIdx.x * 32;
    const int n0 = wave * 32;
    const int r8 = t >> 3;   // 0..31 (x row)
    const int kg = t & 7;    // x col group, cols kg*8..+7

    f32x4 acc[2][2] = {};    // [mt][nt]

    if (t < 32) rank[i0 + t] = 0;

    for (int k0 = 0; k0 < IN_DIM; k0 += 64) {
        {   // x tile 32 x 64: 8 floats per thread, split hi/lo
            const float* gp = &x[(size_t)(i0 + r8) * IN_DIM + k0 + kg * 8];
            float4 f0 = *(const float4*)gp;
            float4 f1 = *(const float4*)(gp + 4);
            float ff[8] = {f0.x, f0.y, f0.z, f0.w, f1.x, f1.y, f1.z, f1.w};
            ushort_t h[8], lo[8];
            #pragma unroll
            for (int e = 0; e < 8; ++e) {
                __hip_bfloat16 hb = __float2bfloat16(ff[e]);
                float hf = __bfloat162float(hb);
                __hip_bfloat16 lb = __float2bfloat16(ff[e] - hf);
                h[e]  = *(ushort_t*)&hb;
                lo[e] = *(ushort_t*)&lb;
            }
            *(uint4*)&xh_s[r8 * LDSS + kg * 8] = *(uint4*)h;
            *(uint4*)&xl_s[r8 * LDSS + kg * 8] = *(uint4*)lo;
        }
        // v tile 128 x 64 hi/lo: 1024 groups of 8 bf16, 4 per thread
        #pragma unroll
        for (int it = 0; it < 4; ++it) {
            int gidx = t + it * 256;
            int row = gidx >> 3, kgg = gidx & 7;
            uint4 hv = *(const uint4*)&vh[(size_t)row * IN_DIM + k0 + kgg * 8];
            uint4 lv = *(const uint4*)&vl[(size_t)row * IN_DIM + k0 + kgg * 8];
            *(uint4*)&vh_s[row * LDSS + kgg * 8] = hv;
            *(uint4*)&vl_s[row * LDSS + kgg * 8] = lv;
        }
        __syncthreads();
        #pragma unroll
        for (int sub = 0; sub < 2; ++sub) {
            int kb = sub * 32 + (lane >> 4) * 8;
            bf16x8 ah[2], al[2], bh[2], bl[2];
            #pragma unroll
            for (int mt = 0; mt < 2; ++mt) {
                int row = mt * 16 + (lane & 15);
                ah[mt] = *(const bf16x8*)&xh_s[row * LDSS + kb];
                al[mt] = *(const bf16x8*)&xl_s[row * LDSS + kb];
            }
            #pragma unroll
            for (int nt = 0; nt < 2; ++nt) {
                int row = n0 + nt * 16 + (lane & 15);
                bh[nt] = *(const bf16x8*)&vh_s[row * LDSS + kb];
                bl[nt] = *(const bf16x8*)&vl_s[row * LDSS + kb];
            }
            #pragma unroll
            for (int mt = 0; mt < 2; ++mt)
                #pragma unroll
                for (int nt = 0; nt < 2; ++nt) {
                    acc[mt][nt] = __builtin_amdgcn_mfma_f32_16x16x32_bf16(ah[mt], bh[nt], acc[mt][nt], 0, 0, 0);
                    acc[mt][nt] = __builtin_amdgcn_mfma_f32_16x16x32_bf16(ah[mt], bl[nt], acc[mt][nt], 0, 0, 0);
                    acc[mt][nt] = __builtin_amdgcn_mfma_f32_16x16x32_bf16(al[mt], bh[nt], acc[mt][nt], 0, 0, 0);
                }
        }
        __syncthreads();
    }

    // ---- epilogue: bias add, store z, keep tile in LDS for s/d ----
    float* zt = (float*)sh;          // 32 x 132 f32 (reuse staging LDS)
    #pragma unroll
    for (int nt = 0; nt < 2; ++nt) {
        int n = n0 + nt * 16 + (lane & 15);
        float bb = b[n];
        #pragma unroll
        for (int mt = 0; mt < 2; ++mt)
            #pragma unroll
            for (int r = 0; r < 4; ++r) {
                int mrow = mt * 16 + (lane >> 4) * 4 + r;
                float val = acc[mt][nt][r] + bb;
                z[(size_t)(i0 + mrow) * F_DIM + n] = val;
                zt[mrow * 132 + n] = val;
            }
    }
    __syncthreads();
    // s/d/keys: 4 waves x 8 rows each
    float awS0 = aw[lane], awS1 = aw[64 + lane];
    float awD0 = aw[F_DIM + lane], awD1 = aw[F_DIM + 64 + lane];
    #pragma unroll
    for (int rr = 0; rr < 8; ++rr) {
        int row = wave * 8 + rr;
        float z0 = zt[row * 132 + lane];
        float z1 = zt[row * 132 + 64 + lane];
        float ss = z0 * awS0 + z1 * awS1;
        float dd = z0 * awD0 + z1 * awD1;
        #pragma unroll
        for (int off = 32; off > 0; off >>= 1) {
            ss += __shfl_xor(ss, off);
            dd += __shfl_xor(dd, off);
        }
        if (lane == 0) {
            int i = i0 + row;
            s[i] = ss;
            d[i] = dd;
            keys[i] = ((ull_t)orderKey(dd) << 32) | (unsigned)i;
        }
    }
}

// ---------------------------------------------------------------------------
// K4: rank[j] = #{k : key_k < key_j}. Keys batched 8 (uniform -> scalar
// loads); grid (48, 24) = 1152 blocks; fire-and-forget atomic partials.
// ---------------------------------------------------------------------------
__global__ __launch_bounds__(256) void k4_rank(const ull_t* __restrict__ keys,
                                               int* __restrict__ rank) {
    int j = blockIdx.x * 256 + threadIdx.x;
    ull_t kj = keys[j];
    const ull_t* p = keys + blockIdx.y * K4T;
    int cr = 0;
    for (int kk = 0; kk < K4T; kk += 8) {
        ull_t kv[8];
        #pragma unroll
        for (int e = 0; e < 8; ++e) kv[e] = p[kk + e];
        #pragma unroll
        for (int e = 0; e < 8; ++e) cr += (kv[e] < kj);
    }
    atomicAdd(&rank[j], cr);
}

// ---------------------------------------------------------------------------
// K5a: scatter into sorted order: perm, ed = exp(d), soi = orderable key
// ---------------------------------------------------------------------------
__global__ __launch_bounds__(256) void k5a_scatter(const float* __restrict__ d,
                                                   const int* __restrict__ rank,
                                                   int* __restrict__ perm,
                                                   float* __restrict__ ed,
                                                   unsigned* __restrict__ soi) {
    int j = blockIdx.x * 256 + threadIdx.x;
    int r = rank[j];
    float dj = d[j];
    perm[r] = j;
    ed[r] = expf(dj);
    soi[r] = orderKey(dj);
}

// ---------------------------------------------------------------------------
// K5b: per-chunk sums over CH=16 sorted rows (768 blocks x 128)
// ---------------------------------------------------------------------------
__global__ __launch_bounds__(128) void k5b_chunksum(const float* __restrict__ z,
                                                    const int* __restrict__ perm,
                                                    const float* __restrict__ ed,
                                                    float* __restrict__ chEZ,
                                                    float* __restrict__ chZ,
                                                    float* __restrict__ chE) {
    int k = blockIdx.x, f = threadIdx.x;
    int p0 = k * CH;
    float aez = 0.f, az = 0.f;
    #pragma unroll 4
    for (int q = 0; q < CH; ++q) {
        float e  = ed[p0 + q];
        float zv = z[(size_t)perm[p0 + q] * F_DIM + f];
        aez = fmaf(e, zv, aez);
        az += zv;
    }
    chEZ[(size_t)k * F_DIM + f] = aez;
    chZ [(size_t)k * F_DIM + f] = az;
    if (f < CH) {
        float e = ed[p0 + f];
        #pragma unroll
        for (int off = 8; off > 0; off >>= 1) e += __shfl_xor(e, off);
        if (f == 0) chE[k] = e;
    }
}

// ---------------------------------------------------------------------------
// K5c: exclusive prefix over NCH=768 chunk sums; totals land at index NCH.
// grid 129 x 64: blocks 0..127 handle one f-column of chEZ and chZ;
// block 128 handles chE. Each lane owns 12 chunks.
// ---------------------------------------------------------------------------
__global__ __launch_bounds__(64) void k5c_scan(float* __restrict__ chEZ,
                                               float* __restrict__ chZ,
                                               float* __restrict__ chE) {
    int bx = blockIdx.x;
    int lane = threadIdx.x;
    int npass = (bx < F_DIM) ? 2 : 1;
    for (int pass = 0; pass < npass; ++pass) {
        float* arr = (bx == F_DIM) ? chE : (pass == 0 ? chEZ : chZ);
        size_t str = (bx == F_DIM) ? 1 : F_DIM;
        size_t col = (bx == F_DIM) ? 0 : (size_t)bx;
        float vv[12];
        #pragma unroll
        for (int e = 0; e < 12; ++e)
            vv[e] = arr[(size_t)(lane * 12 + e) * str + col];
        float run = 0.f;
        #pragma unroll
        for (int e = 0; e < 12; ++e) { float tmp = vv[e]; vv[e] = run; run += tmp; }
        float incl = run;
        #pragma unroll
        for (int off = 1; off < 64; off <<= 1) {
            float o = __shfl_up(incl, off);
            if (lane >= off) incl += o;
        }
        float excl = incl - run;
        #pragma unroll
        for (int e = 0; e < 12; ++e)
            arr[(size_t)(lane * 12 + e) * str + col] = excl + vv[e];
        if (lane == 63)
            arr[(size_t)NCH * str + col] = incl;   // grand total
    }
}

// ---------------------------------------------------------------------------
// K6: per row i —
//   c = upper_bound(soi, orderKey(-s_i))  (binary search, 14 steps)
//   partials at c = chunk prefix[kc] + on-the-fly remainder over <=15 rows
//   z2 = (es*sufEZ + preZ)/(es*sufE + c) + z ; out = softmax(z2)
// ---------------------------------------------------------------------------
__global__ __launch_bounds__(128) void k6_final(const float* __restrict__ z,
                                                const float* __restrict__ s,
                                                const int* __restrict__ perm,
                                                const float* __restrict__ ed,
                                                const unsigned* __restrict__ soi,
                                                const float* __restrict__ chEZ,
                                                const float* __restrict__ chZ,
                                                const float* __restrict__ chE,
                                                float* __restrict__ out) {
    __shared__ float redmx[2], redsum[2];
    int i = blockIdx.x, f = threadIdx.x;
    int wave = f >> 6, lane = f & 63;

    float si = s[i];
    unsigned ot = orderKey(-si);
    int lo = 0, hi = N_ROWS;
    while (lo < hi) {
        int mid = (lo + hi) >> 1;
        if (soi[mid] <= ot) lo = mid + 1; else hi = mid;
    }
    int c = lo;
    int kc = c >> 4, r = c & 15, p0 = kc << 4;

    float bEZ = chEZ[(size_t)kc * F_DIM + f];
    float bZ  = chZ [(size_t)kc * F_DIM + f];
    float bE  = chE[kc];
    for (int q = 0; q < r; ++q) {
        float e  = ed[p0 + q];
        float zv = z[(size_t)perm[p0 + q] * F_DIM + f];
        bEZ = fmaf(e, zv, bEZ);
        bZ += zv;
        bE += e;
    }
    float totE  = chE[NCH];
    float totEZ = chEZ[(size_t)NCH * F_DIM + f];
    float es = expf(si);
    float D   = fmaf(es, totE - bE, (float)c);
    float num = fmaf(es, totEZ - bEZ, bZ);
    float z2  = num / D + z[(size_t)i * F_DIM + f];

    float mx = z2;
    #pragma unroll
    for (int off = 32; off > 0; off >>= 1) mx = fmaxf(mx, __shfl_xor(mx, off));
    if (lane == 0) redmx[wave] = mx;
    __syncthreads();
    mx = fmaxf(redmx[0], redmx[1]);

    float ex = expf(z2 - mx);
    float sm = ex;
    #pragma unroll
    for (int off = 32; off > 0; off >>= 1) sm += __shfl_xor(sm, off);
    if (lane == 0) redsum[wave] = sm;
    __syncthreads();
    sm = redsum[0] + redsum[1];

    out[(size_t)i * F_DIM + f] = ex / sm;
}

// ---------------------------------------------------------------------------
extern "C" void kernel_launch(void* const* d_in, const int* in_sizes, int n_in,
                              void* d_out, int out_size, void* d_ws, size_t ws_size,
                              hipStream_t stream) {
    const float* x  = (const float*)d_in[0];
    const float* v  = (const float*)d_in[1];
    const float* g  = (const float*)d_in[2];
    const float* b  = (const float*)d_in[3];
    const float* aw = (const float*)d_in[4];
    float* out = (float*)d_out;

    float* wsf = (float*)d_ws;
    size_t off = 0;
    float* z     = wsf + off;  off += (size_t)N_ROWS * F_DIM;
    float* s     = wsf + off;  off += N_ROWS;
    float* d     = wsf + off;  off += N_ROWS;
    ull_t* keys  = (ull_t*)(wsf + off);  off += 2 * N_ROWS;
    int*   rank  = (int*)(wsf + off);  off += N_ROWS;
    int*   perm  = (int*)(wsf + off);  off += N_ROWS;
    float* ed    = wsf + off;  off += N_ROWS;
    unsigned* soi = (unsigned*)(wsf + off);  off += N_ROWS;
    float* chEZ  = wsf + off;  off += (size_t)(NCH + 1) * F_DIM;
    float* chZ   = wsf + off;  off += (size_t)(NCH + 1) * F_DIM;
    float* chE   = wsf + off;  off += NCH + 4;
    ushort_t* vh = (ushort_t*)(wsf + off);  off += (F_DIM * IN_DIM) / 2;
    ushort_t* vl = (ushort_t*)(wsf + off);  off += (F_DIM * IN_DIM) / 2;

    k1_prep<<<F_DIM, 64, 0, stream>>>(v, g, vh, vl);
    k2_mfma<<<N_ROWS / 32, 256, 0, stream>>>(x, vh, vl, b, aw, z, s, d, keys, rank);
    k4_rank<<<dim3(N_ROWS / 256, N_ROWS / K4T), 256, 0, stream>>>(keys, rank);
    k5a_scatter<<<N_ROWS / 256, 256, 0, stream>>>(d, rank, perm, ed, soi);
    k5b_chunksum<<<NCH, 128, 0, stream>>>(z, perm, ed, chEZ, chZ, chE);
    k5c_scan<<<F_DIM + 1, 64, 0, stream>>>(chEZ, chZ, chE);
    k6_final<<<N_ROWS, 128, 0, stream>>>(z, s, perm, ed, soi, chEZ, chZ, chE, out);
}